// Round 6
// baseline (236.100 us; speedup 1.0000x reference)
//
#include <hip/hip_runtime.h>

typedef __bf16 bf16x8 __attribute__((ext_vector_type(8)));
typedef float  f32x4  __attribute__((ext_vector_type(4)));
typedef float  f32x8  __attribute__((ext_vector_type(8)));
typedef unsigned short ushort;
typedef ushort us8 __attribute__((ext_vector_type(8)));
typedef ushort us4 __attribute__((ext_vector_type(4)));

constexpr int N_NODES = 50000;
constexpr int N_EDGES = 800000;
constexpr int SLOTS = 64;                     // bucket capacity (mean deg 16, Poisson tail << 64)
constexpr int GE   = N_EDGES / 256;           // 3125 (exact)
constexpr int GMF  = (N_NODES + 63) / 64;     // 782 gemm tiles
constexpr int WBLK = (3 * 9216) / 256;        // 108 (exact) Wt prep blocks
constexpr int AGG_NODES = 32;                 // nodes per agg_gemm block
constexpr int GAGG = (N_NODES + AGG_NODES - 1) / AGG_NODES;  // 1563

__device__ inline ushort bf16b(float f) {
    union { __bf16 b; ushort u; } cv; cv.b = (__bf16)f; return cv.u;
}
__device__ inline f32x8 bf8_to_f32(us8 u) {
    f32x8 r;
#pragma unroll
    for (int i = 0; i < 8; ++i) r[i] = __uint_as_float(((unsigned int)u[i]) << 16);
    return r;
}

// ---------------- count (+rank, coalesced store) + W-prep ----------------
__global__ __launch_bounds__(256) void k_count(const int* __restrict__ dst,
                                               int* __restrict__ cnt,
                                               ushort* __restrict__ rank,
                                               const float* __restrict__ W0,
                                               const float* __restrict__ W1,
                                               const float* __restrict__ W2,
                                               ushort* __restrict__ Wt) {
    const int b = blockIdx.x;
    if (b < GE) {
        int e = b * 256 + threadIdx.x;
        int d = __builtin_nontemporal_load(&dst[e]);
        ushort r = (ushort)atomicAdd(&cnt[d], 1);   // dependent store is COALESCED
        __builtin_nontemporal_store(r, &rank[e]);
    } else {
        int i = (b - GE) * 256 + threadIdx.x;   // 0..27647, exact
        int m = i / 9216, li = i - m * 9216;
        const float* W = (m == 0) ? W0 : (m == 1) ? W1 : W2;
        int k = li / 96, c = li - k * 96;
        Wt[m * 9216 + c * 96 + k] = bf16b(W[li]);   // [k][c] f32 -> [c][k] bf16
    }
}

// ---------------- MFMA (256-thread variant): sX[64x96] @ sW[96x96] ([c][k]) -> Y rows ----------------
// Epilogue pre-scales each output row by rsqrt(deg+1): the agg inner loop then needs NO weights.
__device__ __forceinline__ void mfma_store(const ushort* sX, const ushort* sW,
                                           const int* __restrict__ cnt,
                                           ushort* __restrict__ Y, int rowbase) {
    const int tid = threadIdx.x;
    const int wv = tid >> 6, lane = tid & 63, quad = lane >> 4, l16 = lane & 15;
    f32x4 acc[6];
#pragma unroll
    for (int t = 0; t < 6; ++t) acc[t] = (f32x4){0.f, 0.f, 0.f, 0.f};

    const ushort* ax = sX + (wv * 16 + l16) * 96 + quad * 8;
#pragma unroll
    for (int s = 0; s < 3; ++s) {
        bf16x8 a = *(const bf16x8*)(ax + s * 32);
#pragma unroll
        for (int t = 0; t < 6; ++t) {
            bf16x8 b = *(const bf16x8*)(sW + (t * 16 + l16) * 96 + s * 32 + quad * 8);
            acc[t] = __builtin_amdgcn_mfma_f32_16x16x32_bf16(a, b, acc[t], 0, 0, 0);
        }
    }
    // C/D layout: col = lane&15, row = quad*4 + reg
    const int r0 = rowbase + wv * 16 + quad * 4;
#pragma unroll
    for (int g = 0; g < 4; ++g) {
        int r = r0 + g;
        if (r < N_NODES) {
            float dv = rsqrtf((float)(cnt[r] + 1));
#pragma unroll
            for (int t = 0; t < 6; ++t)
                Y[(size_t)r * 96 + t * 16 + l16] = bf16b(acc[t][g] * dv);
        }
    }
}

// ---------------- fused: gemm layer 1 (blocks [0,GMF)) || csr fill (blocks [GMF,GMF+GE)) ----------------
// gemm blocks FIRST so the long pole starts immediately.
// fill: plain scatter of 2-byte src entries (no cnt gather, no weight pack — dinv folded into gemm).
__global__ __launch_bounds__(256) void k_fill_gemm1(const int* __restrict__ src,
                                                    const int* __restrict__ dst,
                                                    const int* __restrict__ cnt,
                                                    const ushort* __restrict__ rank,
                                                    ushort* __restrict__ csr,
                                                    const float* __restrict__ x,
                                                    const ushort* __restrict__ Wt,
                                                    ushort* __restrict__ H) {
    __shared__ ushort sS[64 * 96 + 96 * 96];   // 30 KB (only gemm blocks use it)
    const int b = blockIdx.x;
    const int tid = threadIdx.x;
    if (b < GMF) {
        ushort* sX = sS;
        ushort* sW = sS + 64 * 96;
        const int rowbase = b * 64;
        for (int i = tid; i < 9216 / 8; i += 256)
            ((uint4*)sW)[i] = ((const uint4*)Wt)[i];
        for (int i = tid; i < 64 * 24; i += 256) {
            int r = i / 24, c4 = i % 24;
            int gr = rowbase + r;
            f32x4 v = (f32x4){0.f, 0.f, 0.f, 0.f};
            if (gr < N_NODES) v = __builtin_nontemporal_load((const f32x4*)(x + (size_t)gr * 96) + c4);
            ushort* p = sX + r * 96 + c4 * 4;
            p[0] = bf16b(v[0]); p[1] = bf16b(v[1]); p[2] = bf16b(v[2]); p[3] = bf16b(v[3]);
        }
        __syncthreads();
        mfma_store(sX, sW, cnt, H, rowbase);
    } else {
        int e = (b - GMF) * 256 + tid;   // GE*256 == N_EDGES, exact
        int s = __builtin_nontemporal_load(&src[e]);
        int d = __builtin_nontemporal_load(&dst[e]);
        ushort rk = __builtin_nontemporal_load(&rank[e]);
        __builtin_nontemporal_store((ushort)s, &csr[(size_t)d * SLOTS + rk]);
    }
}

// ---------------- fused aggregate + GEMM (layers 1->2, 2->3) ----------------
// 384 threads = 32 nodes x 12 chunks of 8 feats; 24 KB LDS.
// Rows of A are PRE-SCALED by rsqrt(deg_src+1) (gemm epilogue) -> inner loop is pure adds.
// 2-byte csr entries (nontemporal) keep the reused A table hot in L2.
__global__ __launch_bounds__(384, 4) void k_agg_gemm(const ushort* __restrict__ A,
                                                     const int* __restrict__ cnt,
                                                     const ushort* __restrict__ csr,
                                                     const float* __restrict__ bias,
                                                     const ushort* __restrict__ Wt,
                                                     ushort* __restrict__ Y) {
    __shared__ ushort sS[AGG_NODES * 96 + 96 * 96];   // 24 KB
    ushort* sX = sS;
    ushort* sW = sS + AGG_NODES * 96;
    const int tid = threadIdx.x;
    const int rowbase = blockIdx.x * AGG_NODES;

    // preload W tile (overlaps with the gather phase below)
    for (int i = tid; i < 9216 / 8; i += 384)
        ((uint4*)sW)[i] = ((const uint4*)Wt)[i];

    const int g = tid / 12;           // node within block: 0..31
    const int c = tid - g * 12;       // feature chunk: 0..11
    const int n = rowbase + g;

    f32x8 acc = (f32x8){0.f, 0.f, 0.f, 0.f, 0.f, 0.f, 0.f, 0.f};
    if (n < N_NODES) {
        const int deg = cnt[n];
        const float dn = rsqrtf((float)(deg + 1));
        us8 a0 = *(const us8*)(A + (size_t)n * 96 + c * 8);   // self row (pre-scaled)

        f32x8 nb = (f32x8){0.f, 0.f, 0.f, 0.f, 0.f, 0.f, 0.f, 0.f};
        const ushort* row = csr + (size_t)n * SLOTS;
        int j = 0;
        // 8-edge unroll: 8 independent gathers in flight per thread
        for (; j + 8 <= deg; j += 8) {
            const us8 q = __builtin_nontemporal_load((const us8*)(row + j));
            const us8 u0 = *(const us8*)(A + (size_t)q[0] * 96 + c * 8);
            const us8 u1 = *(const us8*)(A + (size_t)q[1] * 96 + c * 8);
            const us8 u2 = *(const us8*)(A + (size_t)q[2] * 96 + c * 8);
            const us8 u3 = *(const us8*)(A + (size_t)q[3] * 96 + c * 8);
            const us8 u4 = *(const us8*)(A + (size_t)q[4] * 96 + c * 8);
            const us8 u5 = *(const us8*)(A + (size_t)q[5] * 96 + c * 8);
            const us8 u6 = *(const us8*)(A + (size_t)q[6] * 96 + c * 8);
            const us8 u7 = *(const us8*)(A + (size_t)q[7] * 96 + c * 8);
            nb += bf8_to_f32(u0);
            nb += bf8_to_f32(u1);
            nb += bf8_to_f32(u2);
            nb += bf8_to_f32(u3);
            nb += bf8_to_f32(u4);
            nb += bf8_to_f32(u5);
            nb += bf8_to_f32(u6);
            nb += bf8_to_f32(u7);
        }
        for (; j + 4 <= deg; j += 4) {
            const us4 q = __builtin_nontemporal_load((const us4*)(row + j));
            const us8 u0 = *(const us8*)(A + (size_t)q[0] * 96 + c * 8);
            const us8 u1 = *(const us8*)(A + (size_t)q[1] * 96 + c * 8);
            const us8 u2 = *(const us8*)(A + (size_t)q[2] * 96 + c * 8);
            const us8 u3 = *(const us8*)(A + (size_t)q[3] * 96 + c * 8);
            nb += bf8_to_f32(u0);
            nb += bf8_to_f32(u1);
            nb += bf8_to_f32(u2);
            nb += bf8_to_f32(u3);
        }
        for (; j < deg; ++j) {
            const int s = __builtin_nontemporal_load(row + j);
            const us8 u = *(const us8*)(A + (size_t)s * 96 + c * 8);
            nb += bf8_to_f32(u);
        }
        acc = (nb + bf8_to_f32(a0)) * dn;
#pragma unroll
        for (int f = 0; f < 8; ++f) acc[f] = fmaxf(acc[f] + bias[c * 8 + f], 0.0f);
    }
    // pack post-activation row chunk into sX (zeros for out-of-range nodes)
    {
        us8 o;
#pragma unroll
        for (int f = 0; f < 8; ++f) o[f] = bf16b(acc[f]);
        *(us8*)(sX + g * 96 + c * 8) = o;
    }
    __syncthreads();

    // 6-wave MFMA: 12 output 16x16 tiles (2 rowgroups x 6 coltiles), 2 per wave.
    const int wv = tid >> 6;                  // 0..5
    const int lane = tid & 63, quad = lane >> 4, l16 = lane & 15;
    const int t0 = 2 * wv;                    // even tile index; pair shares rowgroup
    const int rg = t0 / 6;                    // 0..1
    const int ct0 = t0 - rg * 6;              // 0,2,4

    f32x4 acc0 = (f32x4){0.f, 0.f, 0.f, 0.f};
    f32x4 acc1 = (f32x4){0.f, 0.f, 0.f, 0.f};
    const ushort* ax = sX + (rg * 16 + l16) * 96 + quad * 8;
#pragma unroll
    for (int s = 0; s < 3; ++s) {
        bf16x8 a = *(const bf16x8*)(ax + s * 32);
        bf16x8 b0 = *(const bf16x8*)(sW + (ct0 * 16 + l16) * 96 + s * 32 + quad * 8);
        bf16x8 b1 = *(const bf16x8*)(sW + ((ct0 + 1) * 16 + l16) * 96 + s * 32 + quad * 8);
        acc0 = __builtin_amdgcn_mfma_f32_16x16x32_bf16(a, b0, acc0, 0, 0, 0);
        acc1 = __builtin_amdgcn_mfma_f32_16x16x32_bf16(a, b1, acc1, 0, 0, 0);
    }
    const int r0 = rowbase + rg * 16 + quad * 4;
#pragma unroll
    for (int gg = 0; gg < 4; ++gg) {
        int r = r0 + gg;
        if (r < N_NODES) {
            float dv = rsqrtf((float)(cnt[r] + 1));
            Y[(size_t)r * 96 + ct0 * 16 + l16]       = bf16b(acc0[gg] * dv);
            Y[(size_t)r * 96 + (ct0 + 1) * 16 + l16] = bf16b(acc1[gg] * dv);
        }
    }
}

// ---------------- final aggregate + fused fc ----------------
__global__ __launch_bounds__(192) void k_agg_fc(const ushort* __restrict__ A,
                                                const int* __restrict__ cnt,
                                                const ushort* __restrict__ csr,
                                                const float* __restrict__ bias,
                                                float* __restrict__ out4,
                                                const float* __restrict__ Wfc,
                                                const float* __restrict__ bfc) {
    __shared__ float sWfc[384];
    __shared__ float red[16][12][4];
    const int tid = threadIdx.x;
    for (int i = tid; i < 384; i += 192) sWfc[i] = Wfc[i];
    __syncthreads();
    const int g = tid / 12, c = tid % 12;
    const int n = blockIdx.x * 16 + g;

    const int deg = cnt[n];
    const float dn = rsqrtf((float)(deg + 1));
    us8 a0 = *(const us8*)(A + (size_t)n * 96 + c * 8);   // self row (pre-scaled)

    f32x8 nb = (f32x8){0.f, 0.f, 0.f, 0.f, 0.f, 0.f, 0.f, 0.f};
    const ushort* row = csr + (size_t)n * SLOTS;
    int j = 0;
    for (; j + 8 <= deg; j += 8) {
        const us8 q = __builtin_nontemporal_load((const us8*)(row + j));
        const us8 u0 = *(const us8*)(A + (size_t)q[0] * 96 + c * 8);
        const us8 u1 = *(const us8*)(A + (size_t)q[1] * 96 + c * 8);
        const us8 u2 = *(const us8*)(A + (size_t)q[2] * 96 + c * 8);
        const us8 u3 = *(const us8*)(A + (size_t)q[3] * 96 + c * 8);
        const us8 u4 = *(const us8*)(A + (size_t)q[4] * 96 + c * 8);
        const us8 u5 = *(const us8*)(A + (size_t)q[5] * 96 + c * 8);
        const us8 u6 = *(const us8*)(A + (size_t)q[6] * 96 + c * 8);
        const us8 u7 = *(const us8*)(A + (size_t)q[7] * 96 + c * 8);
        nb += bf8_to_f32(u0);
        nb += bf8_to_f32(u1);
        nb += bf8_to_f32(u2);
        nb += bf8_to_f32(u3);
        nb += bf8_to_f32(u4);
        nb += bf8_to_f32(u5);
        nb += bf8_to_f32(u6);
        nb += bf8_to_f32(u7);
    }
    for (; j + 4 <= deg; j += 4) {
        const us4 q = __builtin_nontemporal_load((const us4*)(row + j));
        const us8 u0 = *(const us8*)(A + (size_t)q[0] * 96 + c * 8);
        const us8 u1 = *(const us8*)(A + (size_t)q[1] * 96 + c * 8);
        const us8 u2 = *(const us8*)(A + (size_t)q[2] * 96 + c * 8);
        const us8 u3 = *(const us8*)(A + (size_t)q[3] * 96 + c * 8);
        nb += bf8_to_f32(u0);
        nb += bf8_to_f32(u1);
        nb += bf8_to_f32(u2);
        nb += bf8_to_f32(u3);
    }
    for (; j < deg; ++j) {
        const int s = __builtin_nontemporal_load(row + j);
        const us8 u = *(const us8*)(A + (size_t)s * 96 + c * 8);
        nb += bf8_to_f32(u);
    }
    f32x8 acc = (nb + bf8_to_f32(a0)) * dn;
#pragma unroll
    for (int f = 0; f < 8; ++f) acc[f] = fmaxf(acc[f] + bias[c * 8 + f], 0.0f);

    float p0 = 0.f, p1 = 0.f, p2 = 0.f, p3 = 0.f;
#pragma unroll
    for (int f = 0; f < 8; ++f) {
        const float* wr = sWfc + (c * 8 + f) * 4;
        p0 += acc[f] * wr[0];
        p1 += acc[f] * wr[1];
        p2 += acc[f] * wr[2];
        p3 += acc[f] * wr[3];
    }
    red[g][c][0] = p0; red[g][c][1] = p1; red[g][c][2] = p2; red[g][c][3] = p3;
    __syncthreads();
    if (tid < 64) {
        const int gg = tid >> 2, jj = tid & 3;
        float s = bfc[jj];
#pragma unroll
        for (int cc = 0; cc < 12; ++cc) s += red[gg][cc][jj];
        out4[(size_t)(blockIdx.x * 16 + gg) * 4 + jj] = s;
    }
}

// ---------------- launch ----------------
extern "C" void kernel_launch(void* const* d_in, const int* in_sizes, int n_in,
                              void* d_out, int out_size, void* d_ws, size_t ws_size,
                              hipStream_t stream) {
    const float* x   = (const float*)d_in[0];
    const int*   ei  = (const int*)d_in[1];
    const int*   src = ei;
    const int*   dst = ei + N_EDGES;
    const float* W0  = (const float*)d_in[2];
    const float* b0  = (const float*)d_in[3];
    const float* W1  = (const float*)d_in[4];
    const float* b1  = (const float*)d_in[5];
    const float* W2  = (const float*)d_in[6];
    const float* b2  = (const float*)d_in[7];
    const float* Wfc = (const float*)d_in[8];
    const float* bfc = (const float*)d_in[9];
    float* out = (float*)d_out;

    // workspace layout (16 B-aligned blocks)
    char* w = (char*)d_ws;
    ushort* csr = (ushort*)w;              w += ((size_t)N_NODES * SLOTS * 2 + 15) & ~15ULL;
    int*    cnt  = (int*)w;                w += ((size_t)N_NODES * 4 + 15) & ~15ULL;
    ushort* rank = (ushort*)w;             w += ((size_t)N_EDGES * 2 + 15) & ~15ULL;
    ushort* Wt   = (ushort*)w;             w += ((size_t)3 * 9216 * 2 + 15) & ~15ULL;
    ushort* H    = (ushort*)w;             w += ((size_t)N_NODES * 96 * 2 + 15) & ~15ULL;
    ushort* G    = (ushort*)w;             // N_NODES * 96 bf16 (ping-pong buffer)

    (void)hipMemsetAsync(cnt, 0, (size_t)N_NODES * 4, stream);
    // count (coalesced rank store) + Wt prep
    hipLaunchKernelGGL(k_count, dim3(GE + WBLK), dim3(256), 0, stream,
                       dst, cnt, rank, W0, W1, W2, Wt);
    // gemm layer 1 (blocks first, pre-scaled rows) || 2-byte csr fill -> H
    hipLaunchKernelGGL(k_fill_gemm1, dim3(GMF + GE), dim3(256), 0, stream,
                       src, dst, cnt, rank, csr, x, Wt, H);
    // agg layer 1 + gemm layer 2 -> G
    hipLaunchKernelGGL(k_agg_gemm, dim3(GAGG), dim3(384), 0, stream,
                       H, cnt, csr, b0, Wt + 9216, G);
    // agg layer 2 + gemm layer 3 -> H
    hipLaunchKernelGGL(k_agg_gemm, dim3(GAGG), dim3(384), 0, stream,
                       G, cnt, csr, b1, Wt + 2 * 9216, H);
    // agg layer 3 + fused fc -> out
    hipLaunchKernelGGL(k_agg_fc, dim3(N_NODES / 16), dim3(192), 0, stream,
                       H, cnt, csr, b2, out, Wfc, bfc);
}

// Round 7
// 229.424 us; speedup vs baseline: 1.0291x; 1.0291x over previous
//
#include <hip/hip_runtime.h>

typedef __bf16 bf16x8 __attribute__((ext_vector_type(8)));
typedef float  f32x4  __attribute__((ext_vector_type(4)));
typedef float  f32x8  __attribute__((ext_vector_type(8)));
typedef unsigned short ushort;
typedef ushort us8 __attribute__((ext_vector_type(8)));

constexpr int N_NODES = 50000;
constexpr int N_EDGES = 800000;
constexpr int SLOTS = 64;                     // bucket capacity (mean deg 16, Poisson tail << 64)
constexpr int GE   = N_EDGES / 256;           // 3125 (exact)
constexpr int GMF  = (N_NODES + 63) / 64;     // 782 gemm tiles
constexpr int WBLK = (3 * 9216) / 256;        // 108 (exact) Wt prep blocks
constexpr int AGG_NODES = 32;                 // nodes per agg_gemm block
constexpr int GAGG = (N_NODES + AGG_NODES - 1) / AGG_NODES;  // 1563

__device__ inline float h16f(ushort u) {
    union { _Float16 h; ushort u; } cv; cv.u = u; return (float)cv.h;
}
__device__ inline ushort f16b(float f) {
    union { _Float16 h; ushort u; } cv; cv.h = (_Float16)f; return cv.u;
}
__device__ inline ushort bf16b(float f) {
    union { __bf16 b; ushort u; } cv; cv.b = (__bf16)f; return cv.u;
}
__device__ inline f32x8 bf8_to_f32(us8 u) {
    f32x8 r;
#pragma unroll
    for (int i = 0; i < 8; ++i) r[i] = __uint_as_float(((unsigned int)u[i]) << 16);
    return r;
}

// ---------------- count (+rank, coalesced store) + W-prep ----------------
__global__ __launch_bounds__(256) void k_count(const int* __restrict__ dst,
                                               int* __restrict__ cnt,
                                               ushort* __restrict__ rank,
                                               const float* __restrict__ W0,
                                               const float* __restrict__ W1,
                                               const float* __restrict__ W2,
                                               ushort* __restrict__ Wt) {
    const int b = blockIdx.x;
    if (b < GE) {
        int e = b * 256 + threadIdx.x;
        rank[e] = (ushort)atomicAdd(&cnt[dst[e]], 1);   // dependent store is COALESCED
    } else {
        int i = (b - GE) * 256 + threadIdx.x;   // 0..27647, exact
        int m = i / 9216, li = i - m * 9216;
        const float* W = (m == 0) ? W0 : (m == 1) ? W1 : W2;
        int k = li / 96, c = li - k * 96;
        Wt[m * 9216 + c * 96 + k] = bf16b(W[li]);   // [k][c] f32 -> [c][k] bf16
    }
}

// ---------------- MFMA (256-thread variant): sX[64x96] @ sW[96x96] ([c][k]) -> Y rows ----------------
__device__ __forceinline__ void mfma_store(const ushort* sX, const ushort* sW,
                                           ushort* __restrict__ Y, int rowbase) {
    const int tid = threadIdx.x;
    const int wv = tid >> 6, lane = tid & 63, quad = lane >> 4, l16 = lane & 15;
    f32x4 acc[6];
#pragma unroll
    for (int t = 0; t < 6; ++t) acc[t] = (f32x4){0.f, 0.f, 0.f, 0.f};

    const ushort* ax = sX + (wv * 16 + l16) * 96 + quad * 8;
#pragma unroll
    for (int s = 0; s < 3; ++s) {
        bf16x8 a = *(const bf16x8*)(ax + s * 32);
#pragma unroll
        for (int t = 0; t < 6; ++t) {
            bf16x8 b = *(const bf16x8*)(sW + (t * 16 + l16) * 96 + s * 32 + quad * 8);
            acc[t] = __builtin_amdgcn_mfma_f32_16x16x32_bf16(a, b, acc[t], 0, 0, 0);
        }
    }
    // C/D layout: col = lane&15, row = quad*4 + reg
    const int r0 = rowbase + wv * 16 + quad * 4;
#pragma unroll
    for (int t = 0; t < 6; ++t) {
#pragma unroll
        for (int g = 0; g < 4; ++g) {
            int r = r0 + g;
            if (r < N_NODES) Y[(size_t)r * 96 + t * 16 + l16] = bf16b(acc[t][g]);
        }
    }
}

// ---------------- fused: gemm layer 1 (blocks [0,GMF)) || csr fill (blocks [GMF,GMF+GE)) ----------------
// gemm blocks FIRST so the long pole starts immediately.
// fill: no atomic dependency — plain scatter of packed entries (u16 src | f16 rsqrt(deg_src+1)).
__global__ __launch_bounds__(256) void k_fill_gemm1(const int* __restrict__ src,
                                                    const int* __restrict__ dst,
                                                    const int* __restrict__ cnt,
                                                    const ushort* __restrict__ rank,
                                                    unsigned int* __restrict__ csr,
                                                    const float* __restrict__ x,
                                                    const ushort* __restrict__ Wt,
                                                    ushort* __restrict__ H) {
    __shared__ ushort sS[64 * 96 + 96 * 96];   // 30 KB (only gemm blocks use it)
    const int b = blockIdx.x;
    const int tid = threadIdx.x;
    if (b < GMF) {
        ushort* sX = sS;
        ushort* sW = sS + 64 * 96;
        const int rowbase = b * 64;
        for (int i = tid; i < 9216 / 8; i += 256)
            ((uint4*)sW)[i] = ((const uint4*)Wt)[i];
        for (int i = tid; i < 64 * 24; i += 256) {
            int r = i / 24, c4 = i % 24;
            int gr = rowbase + r;
            float4 v = make_float4(0.f, 0.f, 0.f, 0.f);
            if (gr < N_NODES) v = ((const float4*)(x + (size_t)gr * 96))[c4];
            ushort* p = sX + r * 96 + c4 * 4;
            p[0] = bf16b(v.x); p[1] = bf16b(v.y); p[2] = bf16b(v.z); p[3] = bf16b(v.w);
        }
        __syncthreads();
        mfma_store(sX, sW, H, rowbase);
    } else {
        int e = (b - GMF) * 256 + tid;   // GE*256 == N_EDGES, exact
        int s = src[e], d = dst[e];
        float hs = rsqrtf((float)(cnt[s] + 1));
        unsigned int entry = (unsigned int)(ushort)s | ((unsigned int)f16b(hs) << 16);
        csr[(size_t)d * SLOTS + rank[e]] = entry;
    }
}

// ---------------- fused aggregate + GEMM (layers 1->2, 2->3) ----------------
// 384 threads = 32 nodes x 12 chunks of 8 feats; 24 KB LDS.
// Packed 4B entries: weight = h16f(entry>>16) -> NO per-edge cnt gathers.
// 12-edge main loop: 12 independent gathers in flight per thread (~100 VGPR, under the 128 cap).
__global__ __launch_bounds__(384, 4) void k_agg_gemm(const ushort* __restrict__ A,
                                                     const int* __restrict__ cnt,
                                                     const unsigned int* __restrict__ csr,
                                                     const float* __restrict__ bias,
                                                     const ushort* __restrict__ Wt,
                                                     ushort* __restrict__ Y) {
    __shared__ ushort sS[AGG_NODES * 96 + 96 * 96];   // 24 KB
    ushort* sX = sS;
    ushort* sW = sS + AGG_NODES * 96;
    const int tid = threadIdx.x;
    const int rowbase = blockIdx.x * AGG_NODES;

    // preload W tile (overlaps with the gather phase below)
    for (int i = tid; i < 9216 / 8; i += 384)
        ((uint4*)sW)[i] = ((const uint4*)Wt)[i];

    const int g = tid / 12;           // node within block: 0..31
    const int c = tid - g * 12;       // feature chunk: 0..11
    const int n = rowbase + g;

    f32x8 acc = (f32x8){0.f, 0.f, 0.f, 0.f, 0.f, 0.f, 0.f, 0.f};
    if (n < N_NODES) {
        const int deg = cnt[n];
        const float dn = rsqrtf((float)(deg + 1));
        us8 a0 = *(const us8*)(A + (size_t)n * 96 + c * 8);

        f32x8 nb = (f32x8){0.f, 0.f, 0.f, 0.f, 0.f, 0.f, 0.f, 0.f};
        const unsigned int* row = csr + (size_t)n * SLOTS;
        int j = 0;
        // 12-edge main loop: 12 independent gathers in flight per thread
        for (; j + 12 <= deg; j += 12) {
            const uint4 q0 = *(const uint4*)(row + j);       // broadcast across 12 chunk-threads
            const uint4 q1 = *(const uint4*)(row + j + 4);
            const uint4 q2 = *(const uint4*)(row + j + 8);
            const us8 u0  = *(const us8*)(A + (size_t)(q0.x & 0xFFFFu) * 96 + c * 8);
            const us8 u1  = *(const us8*)(A + (size_t)(q0.y & 0xFFFFu) * 96 + c * 8);
            const us8 u2  = *(const us8*)(A + (size_t)(q0.z & 0xFFFFu) * 96 + c * 8);
            const us8 u3  = *(const us8*)(A + (size_t)(q0.w & 0xFFFFu) * 96 + c * 8);
            const us8 u4  = *(const us8*)(A + (size_t)(q1.x & 0xFFFFu) * 96 + c * 8);
            const us8 u5  = *(const us8*)(A + (size_t)(q1.y & 0xFFFFu) * 96 + c * 8);
            const us8 u6  = *(const us8*)(A + (size_t)(q1.z & 0xFFFFu) * 96 + c * 8);
            const us8 u7  = *(const us8*)(A + (size_t)(q1.w & 0xFFFFu) * 96 + c * 8);
            const us8 u8  = *(const us8*)(A + (size_t)(q2.x & 0xFFFFu) * 96 + c * 8);
            const us8 u9  = *(const us8*)(A + (size_t)(q2.y & 0xFFFFu) * 96 + c * 8);
            const us8 u10 = *(const us8*)(A + (size_t)(q2.z & 0xFFFFu) * 96 + c * 8);
            const us8 u11 = *(const us8*)(A + (size_t)(q2.w & 0xFFFFu) * 96 + c * 8);
            nb += bf8_to_f32(u0)  * h16f((ushort)(q0.x >> 16));
            nb += bf8_to_f32(u1)  * h16f((ushort)(q0.y >> 16));
            nb += bf8_to_f32(u2)  * h16f((ushort)(q0.z >> 16));
            nb += bf8_to_f32(u3)  * h16f((ushort)(q0.w >> 16));
            nb += bf8_to_f32(u4)  * h16f((ushort)(q1.x >> 16));
            nb += bf8_to_f32(u5)  * h16f((ushort)(q1.y >> 16));
            nb += bf8_to_f32(u6)  * h16f((ushort)(q1.z >> 16));
            nb += bf8_to_f32(u7)  * h16f((ushort)(q1.w >> 16));
            nb += bf8_to_f32(u8)  * h16f((ushort)(q2.x >> 16));
            nb += bf8_to_f32(u9)  * h16f((ushort)(q2.y >> 16));
            nb += bf8_to_f32(u10) * h16f((ushort)(q2.z >> 16));
            nb += bf8_to_f32(u11) * h16f((ushort)(q2.w >> 16));
        }
        for (; j + 8 <= deg; j += 8) {
            const uint4 q0 = *(const uint4*)(row + j);
            const uint4 q1 = *(const uint4*)(row + j + 4);
            const us8 u0 = *(const us8*)(A + (size_t)(q0.x & 0xFFFFu) * 96 + c * 8);
            const us8 u1 = *(const us8*)(A + (size_t)(q0.y & 0xFFFFu) * 96 + c * 8);
            const us8 u2 = *(const us8*)(A + (size_t)(q0.z & 0xFFFFu) * 96 + c * 8);
            const us8 u3 = *(const us8*)(A + (size_t)(q0.w & 0xFFFFu) * 96 + c * 8);
            const us8 u4 = *(const us8*)(A + (size_t)(q1.x & 0xFFFFu) * 96 + c * 8);
            const us8 u5 = *(const us8*)(A + (size_t)(q1.y & 0xFFFFu) * 96 + c * 8);
            const us8 u6 = *(const us8*)(A + (size_t)(q1.z & 0xFFFFu) * 96 + c * 8);
            const us8 u7 = *(const us8*)(A + (size_t)(q1.w & 0xFFFFu) * 96 + c * 8);
            nb += bf8_to_f32(u0) * h16f((ushort)(q0.x >> 16));
            nb += bf8_to_f32(u1) * h16f((ushort)(q0.y >> 16));
            nb += bf8_to_f32(u2) * h16f((ushort)(q0.z >> 16));
            nb += bf8_to_f32(u3) * h16f((ushort)(q0.w >> 16));
            nb += bf8_to_f32(u4) * h16f((ushort)(q1.x >> 16));
            nb += bf8_to_f32(u5) * h16f((ushort)(q1.y >> 16));
            nb += bf8_to_f32(u6) * h16f((ushort)(q1.z >> 16));
            nb += bf8_to_f32(u7) * h16f((ushort)(q1.w >> 16));
        }
        for (; j + 4 <= deg; j += 4) {
            const uint4 q = *(const uint4*)(row + j);
            const us8 u0 = *(const us8*)(A + (size_t)(q.x & 0xFFFFu) * 96 + c * 8);
            const us8 u1 = *(const us8*)(A + (size_t)(q.y & 0xFFFFu) * 96 + c * 8);
            const us8 u2 = *(const us8*)(A + (size_t)(q.z & 0xFFFFu) * 96 + c * 8);
            const us8 u3 = *(const us8*)(A + (size_t)(q.w & 0xFFFFu) * 96 + c * 8);
            nb += bf8_to_f32(u0) * h16f((ushort)(q.x >> 16));
            nb += bf8_to_f32(u1) * h16f((ushort)(q.y >> 16));
            nb += bf8_to_f32(u2) * h16f((ushort)(q.z >> 16));
            nb += bf8_to_f32(u3) * h16f((ushort)(q.w >> 16));
        }
        for (; j < deg; ++j) {
            const unsigned int e = row[j];
            const us8 u = *(const us8*)(A + (size_t)(e & 0xFFFFu) * 96 + c * 8);
            nb += bf8_to_f32(u) * h16f((ushort)(e >> 16));
        }
        acc = (nb + bf8_to_f32(a0) * dn) * dn;
#pragma unroll
        for (int f = 0; f < 8; ++f) acc[f] = fmaxf(acc[f] + bias[c * 8 + f], 0.0f);
    }
    // pack post-activation row chunk into sX (zeros for out-of-range nodes)
    {
        us8 o;
#pragma unroll
        for (int f = 0; f < 8; ++f) o[f] = bf16b(acc[f]);
        *(us8*)(sX + g * 96 + c * 8) = o;
    }
    __syncthreads();

    // 6-wave MFMA: 12 output 16x16 tiles (2 rowgroups x 6 coltiles), 2 per wave.
    const int wv = tid >> 6;                  // 0..5
    const int lane = tid & 63, quad = lane >> 4, l16 = lane & 15;
    const int t0 = 2 * wv;                    // even tile index; pair shares rowgroup
    const int rg = t0 / 6;                    // 0..1
    const int ct0 = t0 - rg * 6;              // 0,2,4

    f32x4 acc0 = (f32x4){0.f, 0.f, 0.f, 0.f};
    f32x4 acc1 = (f32x4){0.f, 0.f, 0.f, 0.f};
    const ushort* ax = sX + (rg * 16 + l16) * 96 + quad * 8;
#pragma unroll
    for (int s = 0; s < 3; ++s) {
        bf16x8 a = *(const bf16x8*)(ax + s * 32);
        bf16x8 b0 = *(const bf16x8*)(sW + (ct0 * 16 + l16) * 96 + s * 32 + quad * 8);
        bf16x8 b1 = *(const bf16x8*)(sW + ((ct0 + 1) * 16 + l16) * 96 + s * 32 + quad * 8);
        acc0 = __builtin_amdgcn_mfma_f32_16x16x32_bf16(a, b0, acc0, 0, 0, 0);
        acc1 = __builtin_amdgcn_mfma_f32_16x16x32_bf16(a, b1, acc1, 0, 0, 0);
    }
    const int r0 = rowbase + rg * 16 + quad * 4;
#pragma unroll
    for (int gg = 0; gg < 4; ++gg) {
        int r = r0 + gg;
        if (r < N_NODES) {
            Y[(size_t)r * 96 + ct0 * 16 + l16]       = bf16b(acc0[gg]);
            Y[(size_t)r * 96 + (ct0 + 1) * 16 + l16] = bf16b(acc1[gg]);
        }
    }
}

// ---------------- final aggregate + fused fc ----------------
__global__ __launch_bounds__(192) void k_agg_fc(const ushort* __restrict__ A,
                                                const int* __restrict__ cnt,
                                                const unsigned int* __restrict__ csr,
                                                const float* __restrict__ bias,
                                                float* __restrict__ out4,
                                                const float* __restrict__ Wfc,
                                                const float* __restrict__ bfc) {
    __shared__ float sWfc[384];
    __shared__ float red[16][12][4];
    const int tid = threadIdx.x;
    for (int i = tid; i < 384; i += 192) sWfc[i] = Wfc[i];
    __syncthreads();
    const int g = tid / 12, c = tid % 12;
    const int n = blockIdx.x * 16 + g;

    const int deg = cnt[n];
    const float dn = rsqrtf((float)(deg + 1));
    us8 a0 = *(const us8*)(A + (size_t)n * 96 + c * 8);

    f32x8 nb = (f32x8){0.f, 0.f, 0.f, 0.f, 0.f, 0.f, 0.f, 0.f};
    const unsigned int* row = csr + (size_t)n * SLOTS;
    int j = 0;
    for (; j + 12 <= deg; j += 12) {
        const uint4 q0 = *(const uint4*)(row + j);
        const uint4 q1 = *(const uint4*)(row + j + 4);
        const uint4 q2 = *(const uint4*)(row + j + 8);
        const us8 u0  = *(const us8*)(A + (size_t)(q0.x & 0xFFFFu) * 96 + c * 8);
        const us8 u1  = *(const us8*)(A + (size_t)(q0.y & 0xFFFFu) * 96 + c * 8);
        const us8 u2  = *(const us8*)(A + (size_t)(q0.z & 0xFFFFu) * 96 + c * 8);
        const us8 u3  = *(const us8*)(A + (size_t)(q0.w & 0xFFFFu) * 96 + c * 8);
        const us8 u4  = *(const us8*)(A + (size_t)(q1.x & 0xFFFFu) * 96 + c * 8);
        const us8 u5  = *(const us8*)(A + (size_t)(q1.y & 0xFFFFu) * 96 + c * 8);
        const us8 u6  = *(const us8*)(A + (size_t)(q1.z & 0xFFFFu) * 96 + c * 8);
        const us8 u7  = *(const us8*)(A + (size_t)(q1.w & 0xFFFFu) * 96 + c * 8);
        const us8 u8  = *(const us8*)(A + (size_t)(q2.x & 0xFFFFu) * 96 + c * 8);
        const us8 u9  = *(const us8*)(A + (size_t)(q2.y & 0xFFFFu) * 96 + c * 8);
        const us8 u10 = *(const us8*)(A + (size_t)(q2.z & 0xFFFFu) * 96 + c * 8);
        const us8 u11 = *(const us8*)(A + (size_t)(q2.w & 0xFFFFu) * 96 + c * 8);
        nb += bf8_to_f32(u0)  * h16f((ushort)(q0.x >> 16));
        nb += bf8_to_f32(u1)  * h16f((ushort)(q0.y >> 16));
        nb += bf8_to_f32(u2)  * h16f((ushort)(q0.z >> 16));
        nb += bf8_to_f32(u3)  * h16f((ushort)(q0.w >> 16));
        nb += bf8_to_f32(u4)  * h16f((ushort)(q1.x >> 16));
        nb += bf8_to_f32(u5)  * h16f((ushort)(q1.y >> 16));
        nb += bf8_to_f32(u6)  * h16f((ushort)(q1.z >> 16));
        nb += bf8_to_f32(u7)  * h16f((ushort)(q1.w >> 16));
        nb += bf8_to_f32(u8)  * h16f((ushort)(q2.x >> 16));
        nb += bf8_to_f32(u9)  * h16f((ushort)(q2.y >> 16));
        nb += bf8_to_f32(u10) * h16f((ushort)(q2.z >> 16));
        nb += bf8_to_f32(u11) * h16f((ushort)(q2.w >> 16));
    }
    for (; j + 8 <= deg; j += 8) {
        const uint4 q0 = *(const uint4*)(row + j);
        const uint4 q1 = *(const uint4*)(row + j + 4);
        const us8 u0 = *(const us8*)(A + (size_t)(q0.x & 0xFFFFu) * 96 + c * 8);
        const us8 u1 = *(const us8*)(A + (size_t)(q0.y & 0xFFFFu) * 96 + c * 8);
        const us8 u2 = *(const us8*)(A + (size_t)(q0.z & 0xFFFFu) * 96 + c * 8);
        const us8 u3 = *(const us8*)(A + (size_t)(q0.w & 0xFFFFu) * 96 + c * 8);
        const us8 u4 = *(const us8*)(A + (size_t)(q1.x & 0xFFFFu) * 96 + c * 8);
        const us8 u5 = *(const us8*)(A + (size_t)(q1.y & 0xFFFFu) * 96 + c * 8);
        const us8 u6 = *(const us8*)(A + (size_t)(q1.z & 0xFFFFu) * 96 + c * 8);
        const us8 u7 = *(const us8*)(A + (size_t)(q1.w & 0xFFFFu) * 96 + c * 8);
        nb += bf8_to_f32(u0) * h16f((ushort)(q0.x >> 16));
        nb += bf8_to_f32(u1) * h16f((ushort)(q0.y >> 16));
        nb += bf8_to_f32(u2) * h16f((ushort)(q0.z >> 16));
        nb += bf8_to_f32(u3) * h16f((ushort)(q0.w >> 16));
        nb += bf8_to_f32(u4) * h16f((ushort)(q1.x >> 16));
        nb += bf8_to_f32(u5) * h16f((ushort)(q1.y >> 16));
        nb += bf8_to_f32(u6) * h16f((ushort)(q1.z >> 16));
        nb += bf8_to_f32(u7) * h16f((ushort)(q1.w >> 16));
    }
    for (; j + 4 <= deg; j += 4) {
        const uint4 q = *(const uint4*)(row + j);
        const us8 u0 = *(const us8*)(A + (size_t)(q.x & 0xFFFFu) * 96 + c * 8);
        const us8 u1 = *(const us8*)(A + (size_t)(q.y & 0xFFFFu) * 96 + c * 8);
        const us8 u2 = *(const us8*)(A + (size_t)(q.z & 0xFFFFu) * 96 + c * 8);
        const us8 u3 = *(const us8*)(A + (size_t)(q.w & 0xFFFFu) * 96 + c * 8);
        nb += bf8_to_f32(u0) * h16f((ushort)(q.x >> 16));
        nb += bf8_to_f32(u1) * h16f((ushort)(q.y >> 16));
        nb += bf8_to_f32(u2) * h16f((ushort)(q.z >> 16));
        nb += bf8_to_f32(u3) * h16f((ushort)(q.w >> 16));
    }
    for (; j < deg; ++j) {
        const unsigned int e = row[j];
        const us8 u = *(const us8*)(A + (size_t)(e & 0xFFFFu) * 96 + c * 8);
        nb += bf8_to_f32(u) * h16f((ushort)(e >> 16));
    }
    f32x8 acc = (nb + bf8_to_f32(a0) * dn) * dn;
#pragma unroll
    for (int f = 0; f < 8; ++f) acc[f] = fmaxf(acc[f] + bias[c * 8 + f], 0.0f);

    float p0 = 0.f, p1 = 0.f, p2 = 0.f, p3 = 0.f;
#pragma unroll
    for (int f = 0; f < 8; ++f) {
        const float* wr = sWfc + (c * 8 + f) * 4;
        p0 += acc[f] * wr[0];
        p1 += acc[f] * wr[1];
        p2 += acc[f] * wr[2];
        p3 += acc[f] * wr[3];
    }
    red[g][c][0] = p0; red[g][c][1] = p1; red[g][c][2] = p2; red[g][c][3] = p3;
    __syncthreads();
    if (tid < 64) {
        const int gg = tid >> 2, jj = tid & 3;
        float s = bfc[jj];
#pragma unroll
        for (int cc = 0; cc < 12; ++cc) s += red[gg][cc][jj];
        out4[(size_t)(blockIdx.x * 16 + gg) * 4 + jj] = s;
    }
}

// ---------------- launch ----------------
extern "C" void kernel_launch(void* const* d_in, const int* in_sizes, int n_in,
                              void* d_out, int out_size, void* d_ws, size_t ws_size,
                              hipStream_t stream) {
    const float* x   = (const float*)d_in[0];
    const int*   ei  = (const int*)d_in[1];
    const int*   src = ei;
    const int*   dst = ei + N_EDGES;
    const float* W0  = (const float*)d_in[2];
    const float* b0  = (const float*)d_in[3];
    const float* W1  = (const float*)d_in[4];
    const float* b1  = (const float*)d_in[5];
    const float* W2  = (const float*)d_in[6];
    const float* b2  = (const float*)d_in[7];
    const float* Wfc = (const float*)d_in[8];
    const float* bfc = (const float*)d_in[9];
    float* out = (float*)d_out;

    // workspace layout (16 B-aligned blocks)
    char* w = (char*)d_ws;
    unsigned int* csr = (unsigned int*)w;  w += ((size_t)N_NODES * SLOTS * 4 + 15) & ~15ULL;
    int*    cnt  = (int*)w;                w += ((size_t)N_NODES * 4 + 15) & ~15ULL;
    ushort* rank = (ushort*)w;             w += ((size_t)N_EDGES * 2 + 15) & ~15ULL;
    ushort* Wt   = (ushort*)w;             w += ((size_t)3 * 9216 * 2 + 15) & ~15ULL;
    ushort* H    = (ushort*)w;             w += ((size_t)N_NODES * 96 * 2 + 15) & ~15ULL;
    ushort* G    = (ushort*)w;             // N_NODES * 96 bf16 (ping-pong buffer)

    (void)hipMemsetAsync(cnt, 0, (size_t)N_NODES * 4, stream);
    // count (coalesced rank store) + Wt prep
    hipLaunchKernelGGL(k_count, dim3(GE + WBLK), dim3(256), 0, stream,
                       dst, cnt, rank, W0, W1, W2, Wt);
    // gemm layer 1 (blocks first) || dependency-free csr fill -> H
    hipLaunchKernelGGL(k_fill_gemm1, dim3(GMF + GE), dim3(256), 0, stream,
                       src, dst, cnt, rank, csr, x, Wt, H);
    // agg layer 1 + gemm layer 2 -> G
    hipLaunchKernelGGL(k_agg_gemm, dim3(GAGG), dim3(384), 0, stream,
                       H, cnt, csr, b0, Wt + 9216, G);
    // agg layer 2 + gemm layer 3 -> H
    hipLaunchKernelGGL(k_agg_gemm, dim3(GAGG), dim3(384), 0, stream,
                       G, cnt, csr, b1, Wt + 2 * 9216, H);
    // agg layer 3 + fused fc -> out
    hipLaunchKernelGGL(k_agg_fc, dim3(N_NODES / 16), dim3(192), 0, stream,
                       H, cnt, csr, b2, out, Wfc, bfc);
}

// Round 8
// 217.124 us; speedup vs baseline: 1.0874x; 1.0566x over previous
//
#include <hip/hip_runtime.h>

typedef __bf16 bf16x8 __attribute__((ext_vector_type(8)));
typedef float  f32x4  __attribute__((ext_vector_type(4)));
typedef float  f32x8  __attribute__((ext_vector_type(8)));
typedef unsigned short ushort;
typedef ushort us8 __attribute__((ext_vector_type(8)));

constexpr int N_NODES = 50000;
constexpr int N_EDGES = 800000;
constexpr int SLOTS = 64;                     // bucket capacity (mean deg 16, Poisson tail << 64)
constexpr int GE   = N_EDGES / 256;           // 3125 (exact)
constexpr int GMF  = (N_NODES + 63) / 64;     // 782 gemm tiles
constexpr int ZBLK = (12500 + 255) / 256;     // 49 blocks to zero cnt (uint4)
constexpr int WBLK = (3 * 9216) / 256;        // 108 (exact) Wt prep blocks
constexpr int AGG_NODES = 32;                 // nodes per agg_gemm block
constexpr int GAGG = (N_NODES + AGG_NODES - 1) / AGG_NODES;  // 1563

__device__ inline float h16f(ushort u) {
    union { _Float16 h; ushort u; } cv; cv.u = u; return (float)cv.h;
}
__device__ inline ushort f16b(float f) {
    union { _Float16 h; ushort u; } cv; cv.h = (_Float16)f; return cv.u;
}
__device__ inline ushort bf16b(float f) {
    union { __bf16 b; ushort u; } cv; cv.b = (__bf16)f; return cv.u;
}
__device__ inline f32x8 bf8_to_f32(us8 u) {
    f32x8 r;
#pragma unroll
    for (int i = 0; i < 8; ++i) r[i] = __uint_as_float(((unsigned int)u[i]) << 16);
    return r;
}

// ---------------- init: zero cnt (vectorized) + Wt prep (once) ----------------
// Replaces hipMemsetAsync; Wt is ready before the next dispatch needs it.
__global__ __launch_bounds__(256) void k_init(int* __restrict__ cnt,
                                              const float* __restrict__ W0,
                                              const float* __restrict__ W1,
                                              const float* __restrict__ W2,
                                              ushort* __restrict__ Wt) {
    const int b = blockIdx.x;
    const int tid = threadIdx.x;
    if (b < ZBLK) {
        int i = b * 256 + tid;                 // uint4 index; 12500 total (200000 B exact)
        if (i < 12500)
            ((uint4*)cnt)[i] = make_uint4(0, 0, 0, 0);
    } else {
        int i = (b - ZBLK) * 256 + tid;        // 0..27647, exact
        int m = i / 9216, li = i - m * 9216;
        const float* W = (m == 0) ? W0 : (m == 1) ? W1 : W2;
        int k = li / 96, c = li - k * 96;
        Wt[m * 9216 + c * 96 + k] = bf16b(W[li]);   // [k][c] f32 -> [c][k] bf16
    }
}

// ---------------- MFMA (256-thread variant): sX[64x96] @ sW[96x96] ([c][k]) -> Y rows ----------------
__device__ __forceinline__ void mfma_store(const ushort* sX, const ushort* sW,
                                           ushort* __restrict__ Y, int rowbase) {
    const int tid = threadIdx.x;
    const int wv = tid >> 6, lane = tid & 63, quad = lane >> 4, l16 = lane & 15;
    f32x4 acc[6];
#pragma unroll
    for (int t = 0; t < 6; ++t) acc[t] = (f32x4){0.f, 0.f, 0.f, 0.f};

    const ushort* ax = sX + (wv * 16 + l16) * 96 + quad * 8;
#pragma unroll
    for (int s = 0; s < 3; ++s) {
        bf16x8 a = *(const bf16x8*)(ax + s * 32);
#pragma unroll
        for (int t = 0; t < 6; ++t) {
            bf16x8 b = *(const bf16x8*)(sW + (t * 16 + l16) * 96 + s * 32 + quad * 8);
            acc[t] = __builtin_amdgcn_mfma_f32_16x16x32_bf16(a, b, acc[t], 0, 0, 0);
        }
    }
    // C/D layout: col = lane&15, row = quad*4 + reg
    const int r0 = rowbase + wv * 16 + quad * 4;
#pragma unroll
    for (int t = 0; t < 6; ++t) {
#pragma unroll
        for (int g = 0; g < 4; ++g) {
            int r = r0 + g;
            if (r < N_NODES) Y[(size_t)r * 96 + t * 16 + l16] = bf16b(acc[t][g]);
        }
    }
}

// ---------------- fused: gemm layer 1 (blocks [0,GMF)) || count+rank (blocks [GMF,GMF+GE)) ----------------
// gemm1 has NO dependency on counts -> runs in parallel with the count pass.
// count blocks: atomicAdd + COALESCED rank store only (no dependent random scatter).
__global__ __launch_bounds__(256) void k_count_g1(const int* __restrict__ dst,
                                                  int* __restrict__ cnt,
                                                  ushort* __restrict__ rank,
                                                  const float* __restrict__ x,
                                                  const ushort* __restrict__ Wt,
                                                  ushort* __restrict__ H) {
    __shared__ ushort sS[64 * 96 + 96 * 96];   // 30 KB (only gemm blocks use it)
    const int b = blockIdx.x;
    const int tid = threadIdx.x;
    if (b < GMF) {
        ushort* sX = sS;
        ushort* sW = sS + 64 * 96;
        const int rowbase = b * 64;
        for (int i = tid; i < 9216 / 8; i += 256)
            ((uint4*)sW)[i] = ((const uint4*)Wt)[i];
        for (int i = tid; i < 64 * 24; i += 256) {
            int r = i / 24, c4 = i % 24;
            int gr = rowbase + r;
            float4 v = make_float4(0.f, 0.f, 0.f, 0.f);
            if (gr < N_NODES) v = ((const float4*)(x + (size_t)gr * 96))[c4];
            ushort* p = sX + r * 96 + c4 * 4;
            p[0] = bf16b(v.x); p[1] = bf16b(v.y); p[2] = bf16b(v.z); p[3] = bf16b(v.w);
        }
        __syncthreads();
        mfma_store(sX, sW, H, rowbase);
    } else {
        int e = (b - GMF) * 256 + tid;   // GE*256 == N_EDGES, exact
        rank[e] = (ushort)atomicAdd(&cnt[dst[e]], 1);
    }
}

// ---------------- csr fill: dependency-free scatter of packed entries ----------------
// entry = u16 src | f16 rsqrt(deg_src+1)
__global__ __launch_bounds__(256) void k_fill(const int* __restrict__ src,
                                              const int* __restrict__ dst,
                                              const int* __restrict__ cnt,
                                              const ushort* __restrict__ rank,
                                              unsigned int* __restrict__ csr) {
    int e = blockIdx.x * 256 + threadIdx.x;   // GE*256 == N_EDGES, exact
    int s = src[e], d = dst[e];
    float hs = rsqrtf((float)(cnt[s] + 1));
    unsigned int entry = (unsigned int)(ushort)s | ((unsigned int)f16b(hs) << 16);
    csr[(size_t)d * SLOTS + rank[e]] = entry;
}

// ---------------- fused aggregate + GEMM (layers 1->2, 2->3) ----------------
// 384 threads = 32 nodes x 12 chunks of 8 feats; 24 KB LDS.
// Packed 4B entries: weight = h16f(entry>>16) -> NO per-edge cnt gathers.
__global__ __launch_bounds__(384, 4) void k_agg_gemm(const ushort* __restrict__ A,
                                                     const int* __restrict__ cnt,
                                                     const unsigned int* __restrict__ csr,
                                                     const float* __restrict__ bias,
                                                     const ushort* __restrict__ Wt,
                                                     ushort* __restrict__ Y) {
    __shared__ ushort sS[AGG_NODES * 96 + 96 * 96];   // 24 KB
    ushort* sX = sS;
    ushort* sW = sS + AGG_NODES * 96;
    const int tid = threadIdx.x;
    const int rowbase = blockIdx.x * AGG_NODES;

    // preload W tile (overlaps with the gather phase below)
    for (int i = tid; i < 9216 / 8; i += 384)
        ((uint4*)sW)[i] = ((const uint4*)Wt)[i];

    const int g = tid / 12;           // node within block: 0..31
    const int c = tid - g * 12;       // feature chunk: 0..11
    const int n = rowbase + g;

    f32x8 acc = (f32x8){0.f, 0.f, 0.f, 0.f, 0.f, 0.f, 0.f, 0.f};
    if (n < N_NODES) {
        const int deg = cnt[n];
        const float dn = rsqrtf((float)(deg + 1));
        us8 a0 = *(const us8*)(A + (size_t)n * 96 + c * 8);

        f32x8 nb = (f32x8){0.f, 0.f, 0.f, 0.f, 0.f, 0.f, 0.f, 0.f};
        const unsigned int* row = csr + (size_t)n * SLOTS;
        int j = 0;
        // 8-edge unroll: 8 independent gathers in flight per thread
        for (; j + 8 <= deg; j += 8) {
            const uint4 q0 = *(const uint4*)(row + j);       // broadcast across 12 chunk-threads
            const uint4 q1 = *(const uint4*)(row + j + 4);
            const us8 u0 = *(const us8*)(A + (size_t)(q0.x & 0xFFFFu) * 96 + c * 8);
            const us8 u1 = *(const us8*)(A + (size_t)(q0.y & 0xFFFFu) * 96 + c * 8);
            const us8 u2 = *(const us8*)(A + (size_t)(q0.z & 0xFFFFu) * 96 + c * 8);
            const us8 u3 = *(const us8*)(A + (size_t)(q0.w & 0xFFFFu) * 96 + c * 8);
            const us8 u4 = *(const us8*)(A + (size_t)(q1.x & 0xFFFFu) * 96 + c * 8);
            const us8 u5 = *(const us8*)(A + (size_t)(q1.y & 0xFFFFu) * 96 + c * 8);
            const us8 u6 = *(const us8*)(A + (size_t)(q1.z & 0xFFFFu) * 96 + c * 8);
            const us8 u7 = *(const us8*)(A + (size_t)(q1.w & 0xFFFFu) * 96 + c * 8);
            nb += bf8_to_f32(u0) * h16f((ushort)(q0.x >> 16));
            nb += bf8_to_f32(u1) * h16f((ushort)(q0.y >> 16));
            nb += bf8_to_f32(u2) * h16f((ushort)(q0.z >> 16));
            nb += bf8_to_f32(u3) * h16f((ushort)(q0.w >> 16));
            nb += bf8_to_f32(u4) * h16f((ushort)(q1.x >> 16));
            nb += bf8_to_f32(u5) * h16f((ushort)(q1.y >> 16));
            nb += bf8_to_f32(u6) * h16f((ushort)(q1.z >> 16));
            nb += bf8_to_f32(u7) * h16f((ushort)(q1.w >> 16));
        }
        for (; j + 4 <= deg; j += 4) {
            const uint4 q = *(const uint4*)(row + j);
            const us8 u0 = *(const us8*)(A + (size_t)(q.x & 0xFFFFu) * 96 + c * 8);
            const us8 u1 = *(const us8*)(A + (size_t)(q.y & 0xFFFFu) * 96 + c * 8);
            const us8 u2 = *(const us8*)(A + (size_t)(q.z & 0xFFFFu) * 96 + c * 8);
            const us8 u3 = *(const us8*)(A + (size_t)(q.w & 0xFFFFu) * 96 + c * 8);
            nb += bf8_to_f32(u0) * h16f((ushort)(q.x >> 16));
            nb += bf8_to_f32(u1) * h16f((ushort)(q.y >> 16));
            nb += bf8_to_f32(u2) * h16f((ushort)(q.z >> 16));
            nb += bf8_to_f32(u3) * h16f((ushort)(q.w >> 16));
        }
        for (; j < deg; ++j) {
            const unsigned int e = row[j];
            const us8 u = *(const us8*)(A + (size_t)(e & 0xFFFFu) * 96 + c * 8);
            nb += bf8_to_f32(u) * h16f((ushort)(e >> 16));
        }
        acc = (nb + bf8_to_f32(a0) * dn) * dn;
#pragma unroll
        for (int f = 0; f < 8; ++f) acc[f] = fmaxf(acc[f] + bias[c * 8 + f], 0.0f);
    }
    // pack post-activation row chunk into sX (zeros for out-of-range nodes)
    {
        us8 o;
#pragma unroll
        for (int f = 0; f < 8; ++f) o[f] = bf16b(acc[f]);
        *(us8*)(sX + g * 96 + c * 8) = o;
    }
    __syncthreads();

    // 6-wave MFMA: 12 output 16x16 tiles (2 rowgroups x 6 coltiles), 2 per wave.
    const int wv = tid >> 6;                  // 0..5
    const int lane = tid & 63, quad = lane >> 4, l16 = lane & 15;
    const int t0 = 2 * wv;                    // even tile index; pair shares rowgroup
    const int rg = t0 / 6;                    // 0..1
    const int ct0 = t0 - rg * 6;              // 0,2,4

    f32x4 acc0 = (f32x4){0.f, 0.f, 0.f, 0.f};
    f32x4 acc1 = (f32x4){0.f, 0.f, 0.f, 0.f};
    const ushort* ax = sX + (rg * 16 + l16) * 96 + quad * 8;
#pragma unroll
    for (int s = 0; s < 3; ++s) {
        bf16x8 a = *(const bf16x8*)(ax + s * 32);
        bf16x8 b0 = *(const bf16x8*)(sW + (ct0 * 16 + l16) * 96 + s * 32 + quad * 8);
        bf16x8 b1 = *(const bf16x8*)(sW + ((ct0 + 1) * 16 + l16) * 96 + s * 32 + quad * 8);
        acc0 = __builtin_amdgcn_mfma_f32_16x16x32_bf16(a, b0, acc0, 0, 0, 0);
        acc1 = __builtin_amdgcn_mfma_f32_16x16x32_bf16(a, b1, acc1, 0, 0, 0);
    }
    const int r0 = rowbase + rg * 16 + quad * 4;
#pragma unroll
    for (int gg = 0; gg < 4; ++gg) {
        int r = r0 + gg;
        if (r < N_NODES) {
            Y[(size_t)r * 96 + ct0 * 16 + l16]       = bf16b(acc0[gg]);
            Y[(size_t)r * 96 + (ct0 + 1) * 16 + l16] = bf16b(acc1[gg]);
        }
    }
}

// ---------------- final aggregate + fused fc ----------------
__global__ __launch_bounds__(192) void k_agg_fc(const ushort* __restrict__ A,
                                                const int* __restrict__ cnt,
                                                const unsigned int* __restrict__ csr,
                                                const float* __restrict__ bias,
                                                float* __restrict__ out4,
                                                const float* __restrict__ Wfc,
                                                const float* __restrict__ bfc) {
    __shared__ float sWfc[384];
    __shared__ float red[16][12][4];
    const int tid = threadIdx.x;
    for (int i = tid; i < 384; i += 192) sWfc[i] = Wfc[i];
    __syncthreads();
    const int g = tid / 12, c = tid % 12;
    const int n = blockIdx.x * 16 + g;

    const int deg = cnt[n];
    const float dn = rsqrtf((float)(deg + 1));
    us8 a0 = *(const us8*)(A + (size_t)n * 96 + c * 8);

    f32x8 nb = (f32x8){0.f, 0.f, 0.f, 0.f, 0.f, 0.f, 0.f, 0.f};
    const unsigned int* row = csr + (size_t)n * SLOTS;
    int j = 0;
    for (; j + 8 <= deg; j += 8) {
        const uint4 q0 = *(const uint4*)(row + j);
        const uint4 q1 = *(const uint4*)(row + j + 4);
        const us8 u0 = *(const us8*)(A + (size_t)(q0.x & 0xFFFFu) * 96 + c * 8);
        const us8 u1 = *(const us8*)(A + (size_t)(q0.y & 0xFFFFu) * 96 + c * 8);
        const us8 u2 = *(const us8*)(A + (size_t)(q0.z & 0xFFFFu) * 96 + c * 8);
        const us8 u3 = *(const us8*)(A + (size_t)(q0.w & 0xFFFFu) * 96 + c * 8);
        const us8 u4 = *(const us8*)(A + (size_t)(q1.x & 0xFFFFu) * 96 + c * 8);
        const us8 u5 = *(const us8*)(A + (size_t)(q1.y & 0xFFFFu) * 96 + c * 8);
        const us8 u6 = *(const us8*)(A + (size_t)(q1.z & 0xFFFFu) * 96 + c * 8);
        const us8 u7 = *(const us8*)(A + (size_t)(q1.w & 0xFFFFu) * 96 + c * 8);
        nb += bf8_to_f32(u0) * h16f((ushort)(q0.x >> 16));
        nb += bf8_to_f32(u1) * h16f((ushort)(q0.y >> 16));
        nb += bf8_to_f32(u2) * h16f((ushort)(q0.z >> 16));
        nb += bf8_to_f32(u3) * h16f((ushort)(q0.w >> 16));
        nb += bf8_to_f32(u4) * h16f((ushort)(q1.x >> 16));
        nb += bf8_to_f32(u5) * h16f((ushort)(q1.y >> 16));
        nb += bf8_to_f32(u6) * h16f((ushort)(q1.z >> 16));
        nb += bf8_to_f32(u7) * h16f((ushort)(q1.w >> 16));
    }
    for (; j + 4 <= deg; j += 4) {
        const uint4 q = *(const uint4*)(row + j);
        const us8 u0 = *(const us8*)(A + (size_t)(q.x & 0xFFFFu) * 96 + c * 8);
        const us8 u1 = *(const us8*)(A + (size_t)(q.y & 0xFFFFu) * 96 + c * 8);
        const us8 u2 = *(const us8*)(A + (size_t)(q.z & 0xFFFFu) * 96 + c * 8);
        const us8 u3 = *(const us8*)(A + (size_t)(q.w & 0xFFFFu) * 96 + c * 8);
        nb += bf8_to_f32(u0) * h16f((ushort)(q.x >> 16));
        nb += bf8_to_f32(u1) * h16f((ushort)(q.y >> 16));
        nb += bf8_to_f32(u2) * h16f((ushort)(q.z >> 16));
        nb += bf8_to_f32(u3) * h16f((ushort)(q.w >> 16));
    }
    for (; j < deg; ++j) {
        const unsigned int e = row[j];
        const us8 u = *(const us8*)(A + (size_t)(e & 0xFFFFu) * 96 + c * 8);
        nb += bf8_to_f32(u) * h16f((ushort)(e >> 16));
    }
    f32x8 acc = (nb + bf8_to_f32(a0) * dn) * dn;
#pragma unroll
    for (int f = 0; f < 8; ++f) acc[f] = fmaxf(acc[f] + bias[c * 8 + f], 0.0f);

    float p0 = 0.f, p1 = 0.f, p2 = 0.f, p3 = 0.f;
#pragma unroll
    for (int f = 0; f < 8; ++f) {
        const float* wr = sWfc + (c * 8 + f) * 4;
        p0 += acc[f] * wr[0];
        p1 += acc[f] * wr[1];
        p2 += acc[f] * wr[2];
        p3 += acc[f] * wr[3];
    }
    red[g][c][0] = p0; red[g][c][1] = p1; red[g][c][2] = p2; red[g][c][3] = p3;
    __syncthreads();
    if (tid < 64) {
        const int gg = tid >> 2, jj = tid & 3;
        float s = bfc[jj];
#pragma unroll
        for (int cc = 0; cc < 12; ++cc) s += red[gg][cc][jj];
        out4[(size_t)(blockIdx.x * 16 + gg) * 4 + jj] = s;
    }
}

// ---------------- launch ----------------
extern "C" void kernel_launch(void* const* d_in, const int* in_sizes, int n_in,
                              void* d_out, int out_size, void* d_ws, size_t ws_size,
                              hipStream_t stream) {
    const float* x   = (const float*)d_in[0];
    const int*   ei  = (const int*)d_in[1];
    const int*   src = ei;
    const int*   dst = ei + N_EDGES;
    const float* W0  = (const float*)d_in[2];
    const float* b0  = (const float*)d_in[3];
    const float* W1  = (const float*)d_in[4];
    const float* b1  = (const float*)d_in[5];
    const float* W2  = (const float*)d_in[6];
    const float* b2  = (const float*)d_in[7];
    const float* Wfc = (const float*)d_in[8];
    const float* bfc = (const float*)d_in[9];
    float* out = (float*)d_out;

    // workspace layout (16 B-aligned blocks)
    char* w = (char*)d_ws;
    unsigned int* csr = (unsigned int*)w;  w += ((size_t)N_NODES * SLOTS * 4 + 15) & ~15ULL;
    int*    cnt  = (int*)w;                w += ((size_t)N_NODES * 4 + 15) & ~15ULL;
    ushort* rank = (ushort*)w;             w += ((size_t)N_EDGES * 2 + 15) & ~15ULL;
    ushort* Wt   = (ushort*)w;             w += ((size_t)3 * 9216 * 2 + 15) & ~15ULL;
    ushort* H    = (ushort*)w;             w += ((size_t)N_NODES * 96 * 2 + 15) & ~15ULL;
    ushort* G    = (ushort*)w;             // N_NODES * 96 bf16 (ping-pong buffer)

    // init: zero cnt + Wt prep (replaces memset)
    hipLaunchKernelGGL(k_init, dim3(ZBLK + WBLK), dim3(256), 0, stream,
                       cnt, W0, W1, W2, Wt);
    // gemm layer 1 (independent of counts) || count+rank -> H, cnt, rank
    hipLaunchKernelGGL(k_count_g1, dim3(GMF + GE), dim3(256), 0, stream,
                       dst, cnt, rank, x, Wt, H);
    // csr fill (needs final counts)
    hipLaunchKernelGGL(k_fill, dim3(GE), dim3(256), 0, stream,
                       src, dst, cnt, rank, csr);
    // agg layer 1 + gemm layer 2 -> G
    hipLaunchKernelGGL(k_agg_gemm, dim3(GAGG), dim3(384), 0, stream,
                       H, cnt, csr, b0, Wt + 9216, G);
    // agg layer 2 + gemm layer 3 -> H
    hipLaunchKernelGGL(k_agg_gemm, dim3(GAGG), dim3(384), 0, stream,
                       G, cnt, csr, b1, Wt + 2 * 9216, H);
    // agg layer 3 + fused fc -> out
    hipLaunchKernelGGL(k_agg_fc, dim3(N_NODES / 16), dim3(192), 0, stream,
                       H, cnt, csr, b2, out, Wfc, bfc);
}